// Round 1
// 931.742 us; speedup vs baseline: 1.0343x; 1.0343x over previous
//
#include <hip/hip_runtime.h>

// Problem constants (B=512, C=640, S=14, T=196, H=32)
constexpr int kB = 512;
constexpr int kC = 640;
constexpr int kT = 196;   // tokens
constexpr int kTP = 224;  // tokens padded to 7*32
constexpr int kH = 32;    // MLP hidden
constexpr int kKSTEP = 32; // K staged per iteration (2 MFMA k-steps)
constexpr int kNS = kC / kKSTEP; // 20 stages

typedef __bf16 bf16x8 __attribute__((ext_vector_type(8)));
typedef float  f32x16 __attribute__((ext_vector_type(16)));

__device__ __forceinline__ unsigned f2bfbits(float x) {
  // round-to-nearest-even fp32 -> bf16 bits
  unsigned u = __builtin_bit_cast(unsigned, x);
  return (u + 0x7FFFu + ((u >> 16) & 1u)) >> 16;
}

// ---------------------------------------------------------------------------
// Fused kernel: per-batch corr (MFMA, register-resident) + full attention.
// One block per batch (448 threads = 7 waves). K-loop double-buffers LDS and
// prefetches the next stage's global loads into registers before the single
// per-stage barrier, so HBM latency hides under MFMA+conversion.
// After the K-loop the whole normalized 196x196 corr lives in acc[7][16] per
// wave; all attention math (means, MLPs, logits, softmax) is done from
// registers + small LDS reductions. corr never goes to global memory.
// ---------------------------------------------------------------------------
__global__ __launch_bounds__(448) void fused_corr_attn(
    const float* __restrict__ cf, const float* __restrict__ qf,
    const float* __restrict__ w1c, const float* __restrict__ b1c,
    const float* __restrict__ w2c, const float* __restrict__ b2c,
    const float* __restrict__ w1q, const float* __restrict__ b1q,
    const float* __restrict__ w2q, const float* __restrict__ b2q,
    float* __restrict__ attnC, float* __restrict__ attnQ)
{
  __shared__ int Al[2][(kKSTEP/2) * kTP];   // 2 x 14336 B
  __shared__ int Bl[2][(kKSTEP/2) * kTP];
  __shared__ float ssA[kTP], ssB[kTP], invA[kTP], invB[kTP];
  __shared__ float colsum[kTP], rowsum[kTP];
  __shared__ float hidC[kH], hidQ[kH];
  __shared__ float kernC[kTP], kernQ[kTP];
  __shared__ float lgC[kTP], lgQ[kTP];
  __shared__ float red[256];
  // total ~67.6 KB

  const int b    = blockIdx.x;
  const int tid  = threadIdx.x;
  const int wave = tid >> 6;        // 0..6 : M strip = rows [32w, 32w+32)
  const int lane = tid & 63;
  const int hf   = lane >> 5;       // half-wave
  const int l31  = lane & 31;

  const float4* Ap = (const float4*)(cf + (size_t)b * kC * kT); // row = 49 float4
  const float4* Bp = (const float4*)(qf + (size_t)b * kC * kT);

  const int t4 = tid % 56;          // float4 column (49 real + 7 pad)
  const int kr = tid / 56;          // 0..7
  const bool realcol = (t4 < 49);

  if (tid < kTP) {
    ssA[tid] = 0.f; ssB[tid] = 0.f;
    colsum[tid] = 0.f; lgQ[tid] = 0.f;
  }
  if (tid < kH)        hidC[tid] = 0.f;
  else if (tid < 2*kH) hidQ[tid - kH] = 0.f;

  float4 sa = {0.f,0.f,0.f,0.f}, sb = {0.f,0.f,0.f,0.f};

  f32x16 acc[7];
#pragma unroll
  for (int c = 0; c < 7; ++c)
#pragma unroll
    for (int r = 0; r < 16; ++r) acc[c][r] = 0.f;

  const int mrow = 32 * wave + l31;

  // ---- prologue: prefetch stage 0 into registers ----
  float4 pa0[2], pa1[2], pb0[2], pb1[2];
#pragma unroll
  for (int i = 0; i < 2; ++i) {
    pa0[i] = make_float4(0.f,0.f,0.f,0.f); pa1[i] = pa0[i];
    pb0[i] = pa0[i];                        pb1[i] = pa0[i];
    const int k2 = kr + 8 * i;
    if (realcol) {
      const size_t r0 = (size_t)(2 * k2) * 49 + t4;
      pa0[i] = Ap[r0]; pa1[i] = Ap[r0 + 49];
      pb0[i] = Bp[r0]; pb1[i] = Bp[r0 + 49];
    }
  }

  // ---- K loop: single barrier per stage, LDS double buffered ----
  for (int s = 0; s < kNS; ++s) {
    uint4* Aw = (uint4*)Al[s & 1];
    uint4* Bw = (uint4*)Bl[s & 1];
#pragma unroll
    for (int i = 0; i < 2; ++i) {
      const int k2 = kr + 8 * i;
      const float4 a0 = pa0[i], a1 = pa1[i], b0 = pb0[i], b1 = pb1[i];
      sa.x += a0.x*a0.x + a1.x*a1.x;  sa.y += a0.y*a0.y + a1.y*a1.y;
      sa.z += a0.z*a0.z + a1.z*a1.z;  sa.w += a0.w*a0.w + a1.w*a1.w;
      sb.x += b0.x*b0.x + b1.x*b1.x;  sb.y += b0.y*b0.y + b1.y*b1.y;
      sb.z += b0.z*b0.z + b1.z*b1.z;  sb.w += b0.w*b0.w + b1.w*b1.w;
      uint4 aw, bw;
      aw.x = f2bfbits(a0.x) | (f2bfbits(a1.x) << 16);
      aw.y = f2bfbits(a0.y) | (f2bfbits(a1.y) << 16);
      aw.z = f2bfbits(a0.z) | (f2bfbits(a1.z) << 16);
      aw.w = f2bfbits(a0.w) | (f2bfbits(a1.w) << 16);
      bw.x = f2bfbits(b0.x) | (f2bfbits(b1.x) << 16);
      bw.y = f2bfbits(b0.y) | (f2bfbits(b1.y) << 16);
      bw.z = f2bfbits(b0.z) | (f2bfbits(b1.z) << 16);
      bw.w = f2bfbits(b0.w) | (f2bfbits(b1.w) << 16);
      Aw[k2 * 56 + t4] = aw;           // contiguous across lanes
      Bw[k2 * 56 + t4] = bw;
    }
    // issue next stage's loads; they complete under the MFMA phase below
    if (s + 1 < kNS) {
      const int k0n = (s + 1) * kKSTEP;
#pragma unroll
      for (int i = 0; i < 2; ++i) {
        const int k2 = kr + 8 * i;
        if (realcol) {
          const size_t r0 = (size_t)(k0n + 2 * k2) * 49 + t4;
          pa0[i] = Ap[r0]; pa1[i] = Ap[r0 + 49];
          pb0[i] = Bp[r0]; pb1[i] = Bp[r0 + 49];
        }
      }
    }
    __syncthreads();
    const int* Ar = Al[s & 1];
    const int* Br = Bl[s & 1];
#pragma unroll
    for (int kk = 0; kk < 2; ++kk) {
      const int base = (kk * 8 + hf * 4) * kTP;  // u32 row base for this frag
      int4 av;
      av.x = Ar[base          + mrow];
      av.y = Ar[base + kTP    + mrow];
      av.z = Ar[base + 2*kTP  + mrow];
      av.w = Ar[base + 3*kTP  + mrow];
      bf16x8 af = __builtin_bit_cast(bf16x8, av);
#pragma unroll
      for (int c = 0; c < 7; ++c) {
        const int nrow = 32 * c + l31;
        int4 bv;
        bv.x = Br[base          + nrow];
        bv.y = Br[base + kTP    + nrow];
        bv.z = Br[base + 2*kTP  + nrow];
        bv.w = Br[base + 3*kTP  + nrow];
        bf16x8 bfv = __builtin_bit_cast(bf16x8, bv);
        acc[c] = __builtin_amdgcn_mfma_f32_32x32x16_bf16(af, bfv, acc[c], 0, 0, 0);
      }
    }
    // no second barrier: next stage writes the OTHER buffer; all reads of
    // buf[(s-1)&1] are in program order before barrier(s).
  }

  // ---- inv norms ----
  if (realcol) {
    atomicAdd(&ssA[4*t4+0], sa.x); atomicAdd(&ssA[4*t4+1], sa.y);
    atomicAdd(&ssA[4*t4+2], sa.z); atomicAdd(&ssA[4*t4+3], sa.w);
    atomicAdd(&ssB[4*t4+0], sb.x); atomicAdd(&ssB[4*t4+1], sb.y);
    atomicAdd(&ssB[4*t4+2], sb.z); atomicAdd(&ssB[4*t4+3], sb.w);
  }
  __syncthreads();
  if (tid < kTP) {
    invA[tid] = 1.0f / fmaxf(sqrtf(ssA[tid]), 1e-12f);
    invB[tid] = 1.0f / fmaxf(sqrtf(ssB[tid]), 1e-12f);
  }
  __syncthreads();

  // ---- normalize acc in place: corr[t][u] = raw * invA[t] * invB[u] ----
  // C layout: u = 32c + l31, t = 32*wave + 4*hf + (r&3) + 8*(r>>2)
  float ia[16], ib[7];
#pragma unroll
  for (int r = 0; r < 16; ++r) ia[r] = invA[32*wave + 4*hf + (r&3) + 8*(r>>2)];
#pragma unroll
  for (int c = 0; c < 7; ++c) ib[c] = invB[32*c + l31];
#pragma unroll
  for (int c = 0; c < 7; ++c)
#pragma unroll
    for (int r = 0; r < 16; ++r) acc[c][r] *= ia[r] * ib[c];

  // ---- column sums (class MLP input = mean over t) ----
#pragma unroll
  for (int c = 0; c < 7; ++c) {
    float s = 0.f;
#pragma unroll
    for (int r = 0; r < 16; ++r) s += acc[c][r];
    s += __shfl_xor(s, 32);                  // fold other half-wave
    if (hf == 0) atomicAdd(&colsum[32*c + l31], s);  // 7 waves contend
  }
  // ---- row sums (query MLP input = mean over u) ----
  {
#pragma unroll
    for (int r = 0; r < 16; ++r) {
      float s = 0.f;
#pragma unroll
      for (int c = 0; c < 7; ++c) s += acc[c][r];
#pragma unroll
      for (int m = 1; m < 32; m <<= 1) s += __shfl_xor(s, m);
      if (l31 == 0) rowsum[32*wave + 4*hf + (r&3) + 8*(r>>2)] = s;
    }
  }
  __syncthreads();

  // ---- MLP hidden: class on tid<224 (colsum), query on tid>=224 (rowsum) ----
  {
    const int half = tid / kTP;               // 0: class, 1: query
    const int h    = tid & 31;
    const int grp  = (tid - half * kTP) >> 5; // 0..6, each sums 28 tokens
    const float* w1 = half ? w1q : w1c;
    const float* ms = half ? rowsum : colsum;
    float* hid      = half ? hidQ : hidC;
    float s = 0.f;
    const int u0 = grp * 28;
    for (int u = u0; u < u0 + 28; ++u) s += ms[u] * w1[u * kH + h];
    atomicAdd(&hid[h], s * (1.0f / (float)kT));
  }
  __syncthreads();
  if (tid < kH)        hidC[tid]      = fmaxf(hidC[tid]      + b1c[tid],      0.f);
  else if (tid < 2*kH) hidQ[tid - kH] = fmaxf(hidQ[tid - kH] + b1q[tid - kH], 0.f);
  __syncthreads();

  // ---- MLP output kernels (padded with zeros to 224) ----
  if (tid < kTP) {
    const int u = tid;
    float s = 0.f;
    if (u < kT) {
      s = b2c[u];
      for (int h = 0; h < kH; ++h) s += hidC[h] * w2c[h * kT + u];
    }
    kernC[u] = s;
  } else {
    const int u = tid - kTP;
    float s = 0.f;
    if (u < kT) {
      s = b2q[u];
      for (int h = 0; h < kH; ++h) s += hidQ[h] * w2q[h * kT + u];
    }
    kernQ[u] = s;
  }
  __syncthreads();

  // ---- logits from registers ----
  {
    float kc[7];
#pragma unroll
    for (int c = 0; c < 7; ++c) kc[c] = kernC[32*c + l31];
#pragma unroll
    for (int r = 0; r < 16; ++r) {
      float s = 0.f;
#pragma unroll
      for (int c = 0; c < 7; ++c) s += acc[c][r] * kc[c];
#pragma unroll
      for (int m = 1; m < 32; m <<= 1) s += __shfl_xor(s, m);
      if (l31 == 0) lgC[32*wave + 4*hf + (r&3) + 8*(r>>2)] = s;
    }
    float kq[16];
#pragma unroll
    for (int r = 0; r < 16; ++r) kq[r] = kernQ[32*wave + 4*hf + (r&3) + 8*(r>>2)];
#pragma unroll
    for (int c = 0; c < 7; ++c) {
      float s = 0.f;
#pragma unroll
      for (int r = 0; r < 16; ++r) s += acc[c][r] * kq[r];
      s += __shfl_xor(s, 32);
      if (hf == 0) atomicAdd(&lgQ[32*c + l31], s);
    }
  }
  __syncthreads();

  // ---- softmax over tokens (196), x2 paths; all 448 threads hit barriers ----
  {
    float lv = (tid < kT) ? lgC[tid] * 40.f : -3.4e38f;  // / TEMPERATURE
    if (tid < 256) red[tid] = lv;
    __syncthreads();
    for (int o = 128; o > 0; o >>= 1) {
      if (tid < o) red[tid] = fmaxf(red[tid], red[tid + o]);
      __syncthreads();
    }
    const float mx = red[0];
    __syncthreads();
    const float e = (tid < kT) ? __expf(lv - mx) : 0.f;
    if (tid < 256) red[tid] = e;
    __syncthreads();
    for (int o = 128; o > 0; o >>= 1) {
      if (tid < o) red[tid] += red[tid + o];
      __syncthreads();
    }
    const float inv = 1.0f / red[0];
    if (tid < kT) attnC[(size_t)b * kT + tid] = e * inv;
    __syncthreads();
  }
  {
    float lv = (tid < kT) ? lgQ[tid] * 40.f : -3.4e38f;
    if (tid < 256) red[tid] = lv;
    __syncthreads();
    for (int o = 128; o > 0; o >>= 1) {
      if (tid < o) red[tid] = fmaxf(red[tid], red[tid + o]);
      __syncthreads();
    }
    const float mx = red[0];
    __syncthreads();
    const float e = (tid < kT) ? __expf(lv - mx) : 0.f;
    if (tid < 256) red[tid] = e;
    __syncthreads();
    for (int o = 128; o > 0; o >>= 1) {
      if (tid < o) red[tid] += red[tid + o];
      __syncthreads();
    }
    const float inv = 1.0f / red[0];
    if (tid < kT) attnQ[(size_t)b * kT + tid] = e * inv;
  }
}

// ---------------------------------------------------------------------------
// Kernel 2: out = feat * (1 + attn[b, t]), float4 both sides.
// First half of out = class, second half = query. 196 floats = 49 float4/row.
// ---------------------------------------------------------------------------
__global__ __launch_bounds__(256) void scale_kernel(
    const float4* __restrict__ cf, const float4* __restrict__ qf,
    const float* __restrict__ attnC, const float* __restrict__ attnQ,
    float4* __restrict__ out)
{
  constexpr unsigned NC4 = (unsigned)kB * kC * 49u;  // 16,056,320
  const unsigned i = blockIdx.x * 256u + threadIdx.x; // grid sized exactly 2*NC4
  unsigned j;
  const float4* fp;
  const float* ap;
  if (i < NC4) { j = i;       fp = cf; ap = attnC; }
  else         { j = i - NC4; fp = qf; ap = attnQ; }
  const unsigned col = j % 49u;
  const unsigned bc  = j / 49u;
  const unsigned b   = bc / (unsigned)kC;
  const float4 f = fp[j];
  const float4 a = *(const float4*)(ap + (size_t)b * kT + col * 4u);
  float4 r;
  r.x = f.x * (1.f + a.x);
  r.y = f.y * (1.f + a.y);
  r.z = f.z * (1.f + a.z);
  r.w = f.w * (1.f + a.w);
  out[i] = r;
}

extern "C" void kernel_launch(void* const* d_in, const int* in_sizes, int n_in,
                              void* d_out, int out_size, void* d_ws, size_t ws_size,
                              hipStream_t stream) {
  const float* cf  = (const float*)d_in[0];
  const float* qf  = (const float*)d_in[1];
  const float* cw1 = (const float*)d_in[2];
  const float* cb1 = (const float*)d_in[3];
  const float* cw2 = (const float*)d_in[4];
  const float* cb2 = (const float*)d_in[5];
  const float* qw1 = (const float*)d_in[6];
  const float* qb1 = (const float*)d_in[7];
  const float* qw2 = (const float*)d_in[8];
  const float* qb2 = (const float*)d_in[9];
  float* out = (float*)d_out;

  // workspace: only the attention vectors now (corr never leaves the block)
  float* attn_c = (float*)d_ws;                       // 512*196*4
  float* attn_q = attn_c + (size_t)kB * kT;

  fused_corr_attn<<<kB, 448, 0, stream>>>(cf, qf, cw1, cb1, cw2, cb2,
                                          qw1, qb1, qw2, qb2, attn_c, attn_q);
  constexpr unsigned total4 = 2u * (unsigned)kB * kC * 49u;  // 32,112,640
  scale_kernel<<<total4 / 256u, 256, 0, stream>>>(
      (const float4*)cf, (const float4*)qf, attn_c, attn_q, (float4*)out);
}